// Round 14
// baseline (797.378 us; speedup 1.0000x reference)
//
#include <hip/hip_runtime.h>
#include <hip/hip_bf16.h>

#define TOKENS  2048
#define IN_DIM  4096
#define OUT_DIM 11008
#define NGROUPS 32

// ---- i8 GEMM geometry: 128x128 tile, BK=128 (= 1 scale group), 16x16x64 MFMA,
//      4 waves of 64x64 (2M x 2N), SINGLE 32KB LDS buffer, 3 blocks/CU.
//      r14: prep_b folded into GEMM (B: plain i32 loads -> pack4 -> ASM
//      ds_write_b128 into the proven swizzled layout). r13's NaN closed:
//      (1) B LDS writes are asm volatile (ordered vs LDSR/waitcnt asm; data
//          read at issue -> spill-safe), not plain stores (movable across
//          IntrNoMem s_barrier / no-clobber waitcnt asm);
//      (2) no asm in-flight scale regs: scales are plain loads at loop top
//          (allocator-tracked; r3/r4/r13 spill hazard eliminated);
//      (3) LOADPACK after QUADJ in two SB0-fenced pairs: peak transient
//          unpack regs 32, frags dead -> ~100 VGPR + 64 AGPR accf <= 170 cap.
//      Laws kept: r7 restage-immediately-post-drain; r0 swizzle (0 conflicts);
//      r4 launch_bounds 2nd arg = blocks/CU; r11 no fine-grained XCD flags.
#define BM 128
#define BN 128
#define BKB 128                // i8 elems per row per K-tile = one scale group (=128 ints of w_q)
#define THREADS 256
#define NKT   (IN_DIM / BKB)   // 32 K-tiles
#define BUFB  32768            // single LDS buffer (A 16KB + B 16KB)
#define BOFF  16384            // B region offset within buffer

#define PREPA_BLOCKS  TOKENS                         // 2048
#define PREPSC_BLOCKS (OUT_DIM * NGROUPS / 256)      // 1376
#define PREP_GRID     (PREPA_BLOCKS + PREPSC_BLOCKS) // 3424

using f32x4  = __attribute__((ext_vector_type(4))) float;
using i32x4  = __attribute__((ext_vector_type(4))) int;
using bf16x8 = __attribute__((ext_vector_type(8))) short;

typedef __attribute__((address_space(3))) char as3c;

static __device__ __forceinline__ short f2bf(float f) {
    union { float f; unsigned u; } v; v.f = f;
    unsigned r = v.u + 0x7FFFu + ((v.u >> 16) & 1u);
    return (short)(r >> 16);
}

static __device__ __forceinline__ int pack4(int a, int b, int c, int d) {
    return (a & 255) | ((b & 255) << 8) | ((c & 255) << 16) | ((d & 255) << 24);
}

#define SB0 __builtin_amdgcn_sched_barrier(0)
#define LDSR(dst, addr)   asm volatile("ds_read_b128 %0, %1" : "=v"(dst) : "v"(addr))
#define WAITL(n) do { asm volatile("s_waitcnt lgkmcnt(" #n ")"); SB0; } while (0)
#define WAITV(n) do { asm volatile("s_waitcnt vmcnt(" #n ")");  SB0; } while (0)

// ---- fused prep: A-quant + scale transpose only (prep_b folded into GEMM) ----
__global__ __launch_bounds__(256) void prep_fused(
    const float* __restrict__ x, const float* __restrict__ scales,
    const float* __restrict__ s,
    char* __restrict__ Aq, float* __restrict__ sx, float* __restrict__ scT)
{
    __shared__ float wm[4];
    const int bid = blockIdx.x, t = threadIdx.x;

    if (bid < PREPA_BLOCKS) {
        const int row = bid;
        const float* xp = x + (size_t)row * IN_DIM + t * 16;
        const float* sp = s + t * 16;
        f32x4 v[4];
        float m = 0.f;
        #pragma unroll
        for (int q = 0; q < 4; ++q) {
            f32x4 xv = *(const f32x4*)(xp + q * 4);
            f32x4 sv = *(const f32x4*)(sp + q * 4);
            #pragma unroll
            for (int e = 0; e < 4; ++e) {
                v[q][e] = xv[e] / sv[e];
                m = fmaxf(m, fabsf(v[q][e]));
            }
        }
        #pragma unroll
        for (int off = 32; off; off >>= 1) m = fmaxf(m, __shfl_xor(m, off));
        if ((t & 63) == 0) wm[t >> 6] = m;
        __syncthreads();
        m = fmaxf(fmaxf(wm[0], wm[1]), fmaxf(wm[2], wm[3]));
        m = fmaxf(m, 1e-20f);
        const float inv = 127.0f / m;
        i32x4 pk;
        #pragma unroll
        for (int q = 0; q < 4; ++q)
            pk[q] = pack4((int)rintf(v[q][0] * inv), (int)rintf(v[q][1] * inv),
                          (int)rintf(v[q][2] * inv), (int)rintf(v[q][3] * inv));
        ((i32x4*)(Aq + (size_t)row * IN_DIM))[t] = pk;
        if (t == 0) sx[row] = m * (1.0f / 127.0f);
    } else {
        const int idx = (bid - PREPA_BLOCKS) * 256 + t;   // < 352256 exactly
        const int g = idx / OUT_DIM;
        const int o = idx - g * OUT_DIM;
        scT[idx] = scales[o * NGROUPS + g];
    }
}

// ---- 128x128 i8 GEMM, 4 waves of 64x64, single-buffer, 3 blocks/CU,
//      B repacked in-kernel from w_q i32 ----
__global__ __launch_bounds__(THREADS, 3) void awq_gemm_i8(
    const char* __restrict__ Aq, const int* __restrict__ wq,
    const float* __restrict__ scT, const float* __restrict__ sx,
    const float* __restrict__ bias, float* __restrict__ out)
{
    // per-XCD block map (rb&7 -> XCD round-robin), same as r0
    const int rb = blockIdx.x;                  // grid 1408 = 8 * 176
    const int bm = (rb >> 3) & 15;              // 0..15
    const int bn = (((rb >> 3) >> 4) << 3) + (rb & 7);  // 0..87
    if (bn >= OUT_DIM / BN) return;             // 32 dead pad blocks

    __shared__ char smem[BUFB];                 // 32 KB single buffer
    as3c* ldsb = (as3c*)smem;
    const unsigned lbase = (unsigned)(size_t)ldsb;

    const int tid  = threadIdx.x;
    const int lane = tid & 63;
    const int w    = tid >> 6;        // wave 0..3
    const int wr   = w >> 1;          // 0..1 (M: 2 x 64)
    const int wc   = w & 1;           // 0..1 (N: 2 x 64)
    const int fr   = lane & 15;
    const int fko  = lane >> 4;       // 0..3

    // fragment LDS read bases; slot g holds global granule g^(fr&7)  [r0-proven]
    const int h7 = fr & 7;
    const unsigned swz0 = (unsigned)(((0 * 4 + fko) ^ h7) * 16);
    const unsigned swz1 = (unsigned)(((1 * 4 + fko) ^ h7) * 16);
    const unsigned aB0 = lbase + (wr * 64 + fr) * 128 + swz0;         // + i*2048
    const unsigned aB1 = lbase + (wr * 64 + fr) * 128 + swz1;
    const unsigned bB0 = lbase + BOFF + (wc * 64 + fr) * 128 + swz0;  // + j*2048
    const unsigned bB1 = lbase + BOFF + (wc * 64 + fr) * 128 + swz1;

    // staging: thread -> row tid>>3 (0..31) per sweep, granule tid&7 pre-swizzled
    const int srow = tid >> 3;
    const int sgE  = ((tid & 7) ^ (srow & 7)) * 16;   // granule offset (elements)
    const char* aSrc = Aq + (size_t)(bm * BM + srow) * IN_DIM + sgE;
    const int*  bW   = wq + (size_t)(bn * BN + srow) * IN_DIM + sgE;  // i32 source

    // B write base: linear (matches what global_load_lds produced in r12)
    const unsigned wAddr = lbase + BOFF + (unsigned)(tid * 16);

    // scales: lane's 4 columns are wc*64 + j*16 + fr, j=0..3 (16 floats apart)
    const float* scp = scT + bn * BN + wc * 64 + fr;

#define STG_A(Q, KT) __builtin_amdgcn_global_load_lds( \
    (const __attribute__((address_space(1))) void*)(const void*)(aSrc + (size_t)((Q) * 32) * IN_DIM + (KT) * BKB), \
    (__attribute__((address_space(3))) void*)(ldsb + (Q) * 4096 + tid * 16), 16, 0, 0)
#define STG_TILE_A(KT) do { STG_A(0, KT); STG_A(1, KT); STG_A(2, KT); STG_A(3, KT); SB0; } while (0)

// load+pack two 32-row sweeps of w_q for K-tile KT into pkB[QA],pkB[QB]
#define LOADPACK2(QA, QB, KT) do { \
    const int* wpA = bW + (size_t)((QA) * 32) * IN_DIM + (size_t)(KT) * BKB; \
    const int* wpB = bW + (size_t)((QB) * 32) * IN_DIM + (size_t)(KT) * BKB; \
    i32x4 u0 = ((const i32x4*)wpA)[0], u1 = ((const i32x4*)wpA)[1]; \
    i32x4 u2 = ((const i32x4*)wpA)[2], u3 = ((const i32x4*)wpA)[3]; \
    i32x4 v0 = ((const i32x4*)wpB)[0], v1 = ((const i32x4*)wpB)[1]; \
    i32x4 v2 = ((const i32x4*)wpB)[2], v3 = ((const i32x4*)wpB)[3]; \
    pkB[QA][0] = pack4(u0[0], u0[1], u0[2], u0[3]); \
    pkB[QA][1] = pack4(u1[0], u1[1], u1[2], u1[3]); \
    pkB[QA][2] = pack4(u2[0], u2[1], u2[2], u2[3]); \
    pkB[QA][3] = pack4(u3[0], u3[1], u3[2], u3[3]); \
    pkB[QB][0] = pack4(v0[0], v0[1], v0[2], v0[3]); \
    pkB[QB][1] = pack4(v1[0], v1[1], v1[2], v1[3]); \
    pkB[QB][2] = pack4(v2[0], v2[1], v2[2], v2[3]); \
    pkB[QB][3] = pack4(v3[0], v3[1], v3[2], v3[3]); \
    SB0; } while (0)

// B restage: asm ds_write_b128 (volatile: ordered vs LDSR/waitcnt; inputs read
// at issue -> no in-flight-dest spill hazard). Same layout as r12's STG_B DMA.
#define DSWRITE_B() do { \
    asm volatile("ds_write_b128 %0, %1"              :: "v"(wAddr), "v"(pkB[0])); \
    asm volatile("ds_write_b128 %0, %1 offset:4096"  :: "v"(wAddr), "v"(pkB[1])); \
    asm volatile("ds_write_b128 %0, %1 offset:8192"  :: "v"(wAddr), "v"(pkB[2])); \
    asm volatile("ds_write_b128 %0, %1 offset:12288" :: "v"(wAddr), "v"(pkB[3])); \
    SB0; } while (0)

// column j: 4 slabs x (2 chained MFMAs) + dequant into f32 master acc
#define QUADJ(J, CJ) do { \
    _Pragma("unroll") \
    for (int i = 0; i < 4; ++i) { \
        i32x4 tq = __builtin_amdgcn_mfma_i32_16x16x64_i8(a[i][0], b[J][0], (i32x4){0,0,0,0}, 0, 0, 0); \
        tq       = __builtin_amdgcn_mfma_i32_16x16x64_i8(a[i][1], b[J][1], tq, 0, 0, 0); \
        _Pragma("unroll") \
        for (int e = 0; e < 4; ++e) accf[i][J][e] += (float)tq[e] * (CJ); \
    } } while (0)

    f32x4 accf[4][4];
    #pragma unroll
    for (int i = 0; i < 4; ++i)
        #pragma unroll
        for (int j = 0; j < 4; ++j) accf[i][j] = (f32x4){0.f, 0.f, 0.f, 0.f};

    i32x4 pkB[4];

    // prologue: B0 pack+write; A0 via DMA; preload pkB for tile 1
    LOADPACK2(0, 1, 0); LOADPACK2(2, 3, 0);
    DSWRITE_B();
    STG_TILE_A(0);
    WAITL(0);                       // ds_writes drained before pkB reuse
    LOADPACK2(0, 1, 1); LOADPACK2(2, 3, 1);   // pkB now holds tile 1
    WAITV(0);
    __builtin_amdgcn_s_barrier();
    SB0;

    for (int t = 0; t < NKT; ++t) {
        const bool haveN = (t + 1 < NKT);

        // group-t scales: plain loads (allocator-tracked; L2-hot scT)
        const float* scg = scp + (size_t)t * OUT_DIM;
        const float c0 = scg[0], c1 = scg[16], c2 = scg[32], c3 = scg[48];

        i32x4 a[4][2], b[4][2];
        // 16 ds_reads of tile t (square waves: A x2, B x2 re-read)
        #pragma unroll
        for (int i = 0; i < 4; ++i) {
            LDSR(a[i][0], aB0 + i * 2048);
            LDSR(a[i][1], aB1 + i * 2048);
        }
        #pragma unroll
        for (int j = 0; j < 4; ++j) {
            LDSR(b[j][0], bB0 + j * 2048);
            LDSR(b[j][1], bB1 + j * 2048);
        }
        WAITL(0);                       // this wave's frags in regs
        __builtin_amdgcn_s_barrier();   // all waves done reading -> buffer free
        SB0;                            // nothing may hoist above the barrier

        // restage IMMEDIATELY post-drain (r7 L2 law): B ds_writes (pkB = t+1),
        // then A DMA
        if (haveN) {
            DSWRITE_B();
            STG_TILE_A(t + 1);
        }
        SB0;

        __builtin_amdgcn_s_setprio(1);
        QUADJ(0, c0); QUADJ(1, c1); QUADJ(2, c2); QUADJ(3, c3);
        __builtin_amdgcn_s_setprio(0);

        // preload+pack B for tile t+2 (frags dead here; 2 SB0-fenced pairs cap
        // transient regs at 32)
        if (t + 2 < NKT) { LOADPACK2(0, 1, t + 2); LOADPACK2(2, 3, t + 2); }

        WAITV(0); WAITL(0);             // A DMA + B ds_writes landed
        __builtin_amdgcn_s_barrier();
        SB0;
    }

    // ---- epilogue: * sx[row], + bias[col] ----
    #pragma unroll
    for (int i = 0; i < 4; ++i) {
        const int row = bm * BM + wr * 64 + i * 16 + fko * 4;
        const f32x4 sxv = *(const f32x4*)(sx + row);
        #pragma unroll
        for (int j = 0; j < 4; ++j) {
            const int col = bn * BN + wc * 64 + j * 16 + fr;
            const float bv = bias[col];
            #pragma unroll
            for (int e = 0; e < 4; ++e)
                out[(size_t)(row + e) * OUT_DIM + col] = accf[i][j][e] * sxv[e] + bv;
        }
    }

#undef STG_A
#undef STG_TILE_A
#undef LOADPACK2
#undef DSWRITE_B
#undef QUADJ
}

// ---- fallback (no workspace): round-1 proven kernel ----
__global__ __launch_bounds__(256) void awq_gemm_fb(
    const float* __restrict__ x, const int* __restrict__ wq,
    const float* __restrict__ scales, const float* __restrict__ s,
    const float* __restrict__ bias, float* __restrict__ out)
{
    __shared__ short As[128][32];
    __shared__ short Bs[128][32];
    const int tid = threadIdx.x, lane = tid & 63, wave = tid >> 6;
    const int nbn = OUT_DIM / 128;
    const int bm = blockIdx.x / nbn, bn = blockIdx.x % nbn;
    const int srow = tid >> 1, scol = (tid & 1) * 16;
    const int wm = (wave >> 1) * 64, wn = (wave & 1) * 64;
    f32x4 acc[4][4];
    #pragma unroll
    for (int i = 0; i < 4; ++i)
        #pragma unroll
        for (int j = 0; j < 4; ++j) acc[i][j] = (f32x4){0.f, 0.f, 0.f, 0.f};
    const float* xrow = x + (size_t)(bm * 128 + srow) * IN_DIM;
    const int* wrow = wq + (size_t)(bn * 128 + srow) * IN_DIM;
    const float* scrow = scales + (size_t)(bn * 128 + srow) * NGROUPS;
    const int fr = lane & 15, fk = (lane >> 4) * 8, fq = lane >> 4;
    for (int kt = 0; kt < IN_DIM / 32; ++kt) {
        const int k0 = kt * 32;
        {
            const float* xp = xrow + k0 + scol;
            const float* sp = s + k0 + scol;
            short tmp[16];
            #pragma unroll
            for (int q = 0; q < 4; ++q) {
                f32x4 xv = *(const f32x4*)(xp + q * 4);
                f32x4 sv = *(const f32x4*)(sp + q * 4);
                #pragma unroll
                for (int e = 0; e < 4; ++e) tmp[q * 4 + e] = f2bf(xv[e] / sv[e]);
            }
            #pragma unroll
            for (int e = 0; e < 16; ++e) As[srow][scol + e] = tmp[e];
        }
        {
            const float sc = scrow[kt >> 2];
            const int* wp = wrow + k0 + scol;
            short tmp[16];
            #pragma unroll
            for (int q = 0; q < 4; ++q) {
                i32x4 wv = *(const i32x4*)(wp + q * 4);
                #pragma unroll
                for (int e = 0; e < 4; ++e) tmp[q * 4 + e] = f2bf((float)wv[e] * sc);
            }
            #pragma unroll
            for (int e = 0; e < 16; ++e) Bs[srow][scol + e] = tmp[e];
        }
        __syncthreads();
        bf16x8 a[4], b[4];
        #pragma unroll
        for (int i = 0; i < 4; ++i) a[i] = *(const bf16x8*)&As[wm + i * 16 + fr][fk];
        #pragma unroll
        for (int j = 0; j < 4; ++j) b[j] = *(const bf16x8*)&Bs[wn + j * 16 + fr][fk];
        #pragma unroll
        for (int i = 0; i < 4; ++i)
            #pragma unroll
            for (int j = 0; j < 4; ++j)
                acc[i][j] = __builtin_amdgcn_mfma_f32_16x16x32_bf16(a[i], b[j], acc[i][j], 0, 0, 0);
        __syncthreads();
    }
    #pragma unroll
    for (int i = 0; i < 4; ++i) {
        const int row = bm * 128 + wm + i * 16 + fq * 4;
        #pragma unroll
        for (int j = 0; j < 4; ++j) {
            const int col = bn * 128 + wn + j * 16 + fr;
            const float bv = bias[col];
            #pragma unroll
            for (int e = 0; e < 4; ++e)
                out[(size_t)(row + e) * OUT_DIM + col] = acc[i][j][e] + bv;
        }
    }
}

extern "C" void kernel_launch(void* const* d_in, const int* in_sizes, int n_in,
                              void* d_out, int out_size, void* d_ws, size_t ws_size,
                              hipStream_t stream) {
    const float* x      = (const float*)d_in[0];
    const int*   wq     = (const int*)  d_in[1];
    const float* scales = (const float*)d_in[2];
    const float* s      = (const float*)d_in[3];
    const float* bias   = (const float*)d_in[4];
    float* out = (float*)d_out;

    // ws layout (16B-aligned): Aq 8MB | sx 8KB | scT 1.4MB   (Bq eliminated)
    const size_t off_sx = (size_t)TOKENS * IN_DIM;             // 8388608
    const size_t off_sc = off_sx + 8192;
    const size_t need   = off_sc + (size_t)OUT_DIM * NGROUPS * 4;  // ~9.8MB

    if (ws_size >= need) {
        char*  Aq  = (char*)d_ws;
        float* sxw = (float*)((char*)d_ws + off_sx);
        float* scT = (float*)((char*)d_ws + off_sc);
        prep_fused<<<PREP_GRID, 256, 0, stream>>>(x, scales, s, Aq, sxw, scT);
        awq_gemm_i8<<<1408, THREADS, 0, stream>>>(Aq, wq, scT, sxw, bias, out);
    } else {
        awq_gemm_fb<<<(TOKENS / 128) * (OUT_DIM / 128), 256, 0, stream>>>(x, wq, scales, s, bias, out);
    }
}

// Round 15
// 172.824 us; speedup vs baseline: 4.6138x; 4.6138x over previous
//
#include <hip/hip_runtime.h>
#include <hip/hip_bf16.h>

#define TOKENS  2048
#define IN_DIM  4096
#define OUT_DIM 11008
#define NGROUPS 32

// ---- i8 GEMM geometry: 128x128 tile, BK=128 (= 1 scale group), 16x16x64 MFMA,
//      4 waves of 64x64 (2M x 2N), SINGLE 32KB LDS buffer, 3 blocks/CU.
//      SESSION-BEST CONFIG (r12: 173.5us total, GEMM 130us; reproduced twice).
//      Final session laws:
//      - r7: full-drain -> restage -> compute phase order is load-bearing for L2
//      - r0: 128B LDS rows + g^(r&7) granule swizzle = 0 bank conflicts
//      - r5/r14: B must be pre-packed i8 + staged via global_load_lds
//        (per-lane global fragment/repack loads = TA-port + spill disasters)
//      - r4/r10: launch_bounds 2nd arg = blocks/CU; budget must count
//        AGPR-banked accf (64) against the cap (r9 true footprint ~148 <= 170)
//      - r11: no fine-grained cross-XCD flags (~us per release/acquire)
//      - r13/r14: in-GEMM i32->i8 repack dead (ordering hazard / scratch spill)
#define BM 128
#define BN 128
#define BKB 128                // i8 elems (=bytes) per row per K-tile = one quant group
#define THREADS 256
#define NKT   (IN_DIM / BKB)   // 32 K-tiles
#define BUFB  32768            // single LDS buffer (A 16KB + B 16KB)
#define BOFF  16384            // B region offset within buffer

#define PREPA_BLOCKS  TOKENS                         // 2048
#define PREPB_BLOCKS  (OUT_DIM * IN_DIM / 16 / 256)  // 11008
#define PREPSC_BLOCKS (OUT_DIM * NGROUPS / 256)      // 1376
#define PREP_GRID     (PREPA_BLOCKS + PREPB_BLOCKS + PREPSC_BLOCKS)  // 14432

using f32x4  = __attribute__((ext_vector_type(4))) float;
using i32x4  = __attribute__((ext_vector_type(4))) int;
using bf16x8 = __attribute__((ext_vector_type(8))) short;

typedef __attribute__((address_space(3))) char as3c;

static __device__ __forceinline__ short f2bf(float f) {
    union { float f; unsigned u; } v; v.f = f;
    unsigned r = v.u + 0x7FFFu + ((v.u >> 16) & 1u);
    return (short)(r >> 16);
}

static __device__ __forceinline__ int pack4(int a, int b, int c, int d) {
    return (a & 255) | ((b & 255) << 8) | ((c & 255) << 16) | ((d & 255) << 24);
}

#define SB0 __builtin_amdgcn_sched_barrier(0)
#define LDSR(dst, addr)   asm volatile("ds_read_b128 %0, %1" : "=v"(dst) : "v"(addr))
#define WAITL(n) do { asm volatile("s_waitcnt lgkmcnt(" #n ")"); SB0; } while (0)
#define WAITV(n) do { asm volatile("s_waitcnt vmcnt(" #n ")");  SB0; } while (0)

// ---- fused prep: one launch does all three independent passes (r8, proven) ----
__global__ __launch_bounds__(256) void prep_fused(
    const float* __restrict__ x, const int* __restrict__ wq,
    const float* __restrict__ scales, const float* __restrict__ s,
    char* __restrict__ Aq, float* __restrict__ sx,
    char* __restrict__ Bq, float* __restrict__ scT)
{
    __shared__ float wm[4];
    const int bid = blockIdx.x, t = threadIdx.x;

    if (bid < PREPA_BLOCKS) {
        const int row = bid;
        const float* xp = x + (size_t)row * IN_DIM + t * 16;
        const float* sp = s + t * 16;
        f32x4 v[4];
        float m = 0.f;
        #pragma unroll
        for (int q = 0; q < 4; ++q) {
            f32x4 xv = *(const f32x4*)(xp + q * 4);
            f32x4 sv = *(const f32x4*)(sp + q * 4);
            #pragma unroll
            for (int e = 0; e < 4; ++e) {
                v[q][e] = xv[e] / sv[e];
                m = fmaxf(m, fabsf(v[q][e]));
            }
        }
        #pragma unroll
        for (int off = 32; off; off >>= 1) m = fmaxf(m, __shfl_xor(m, off));
        if ((t & 63) == 0) wm[t >> 6] = m;
        __syncthreads();
        m = fmaxf(fmaxf(wm[0], wm[1]), fmaxf(wm[2], wm[3]));
        m = fmaxf(m, 1e-20f);
        const float inv = 127.0f / m;
        i32x4 pk;
        #pragma unroll
        for (int q = 0; q < 4; ++q)
            pk[q] = pack4((int)rintf(v[q][0] * inv), (int)rintf(v[q][1] * inv),
                          (int)rintf(v[q][2] * inv), (int)rintf(v[q][3] * inv));
        ((i32x4*)(Aq + (size_t)row * IN_DIM))[t] = pk;
        if (t == 0) sx[row] = m * (1.0f / 127.0f);
    } else if (bid < PREPA_BLOCKS + PREPB_BLOCKS) {
        const int idx = (bid - PREPA_BLOCKS) * 256 + t;   // 16 elems each
        const int* wp = wq + (size_t)idx * 16;
        i32x4 w0 = *(const i32x4*)wp, w1 = *(const i32x4*)(wp + 4);
        i32x4 w2 = *(const i32x4*)(wp + 8), w3 = *(const i32x4*)(wp + 12);
        i32x4 pk;
        pk[0] = pack4(w0[0], w0[1], w0[2], w0[3]);
        pk[1] = pack4(w1[0], w1[1], w1[2], w1[3]);
        pk[2] = pack4(w2[0], w2[1], w2[2], w2[3]);
        pk[3] = pack4(w3[0], w3[1], w3[2], w3[3]);
        ((i32x4*)Bq)[idx] = pk;
    } else {
        const int idx = (bid - PREPA_BLOCKS - PREPB_BLOCKS) * 256 + t;
        const int g = idx / OUT_DIM;
        const int o = idx - g * OUT_DIM;
        scT[idx] = scales[o * NGROUPS + g];
    }
}

// ---- 128x128 i8 GEMM, 4 waves of 64x64, single-buffer, 3 blocks/CU ----
__global__ __launch_bounds__(THREADS, 3) void awq_gemm_i8(
    const char* __restrict__ Aq, const char* __restrict__ Bq,
    const float* __restrict__ scT, const float* __restrict__ sx,
    const float* __restrict__ bias, float* __restrict__ out)
{
    // per-XCD block map (rb&7 -> XCD round-robin), same as r0
    const int rb = blockIdx.x;                  // grid 1408 = 8 * 176
    const int bm = (rb >> 3) & 15;              // 0..15
    const int bn = (((rb >> 3) >> 4) << 3) + (rb & 7);  // 0..87
    if (bn >= OUT_DIM / BN) return;             // 32 dead pad blocks

    __shared__ char smem[BUFB];                 // 32 KB single buffer
    as3c* ldsb = (as3c*)smem;
    const unsigned lbase = (unsigned)(size_t)ldsb;

    const int tid  = threadIdx.x;
    const int lane = tid & 63;
    const int w    = tid >> 6;        // wave 0..3
    const int wr   = w >> 1;          // 0..1 (M: 2 x 64)
    const int wc   = w & 1;           // 0..1 (N: 2 x 64)
    const int fr   = lane & 15;
    const int fko  = lane >> 4;       // 0..3

    // fragment LDS read bases; slot g holds global granule g^(fr&7)  [r0-proven]
    const int h7 = fr & 7;
    const unsigned swz0 = (unsigned)(((0 * 4 + fko) ^ h7) * 16);
    const unsigned swz1 = (unsigned)(((1 * 4 + fko) ^ h7) * 16);
    const unsigned aB0 = lbase + (wr * 64 + fr) * 128 + swz0;         // + i*2048
    const unsigned aB1 = lbase + (wr * 64 + fr) * 128 + swz1;
    const unsigned bB0 = lbase + BOFF + (wc * 64 + fr) * 128 + swz0;  // + j*2048
    const unsigned bB1 = lbase + BOFF + (wc * 64 + fr) * 128 + swz1;

    // staging: thread -> row tid>>3 (0..31) per sweep, granule tid&7 pre-swizzled
    const int srow = tid >> 3;
    const int sg   = ((tid & 7) ^ (srow & 7)) * 16;
    const char* aSrc = Aq + (size_t)(bm * BM + srow) * IN_DIM + sg;
    const char* bSrc = Bq + (size_t)(bn * BN + srow) * IN_DIM + sg;

    // scales: lane's 4 columns are wc*64 + j*16 + fr, j=0..3 (stride 64 B)
    const float* scp = scT + bn * BN + wc * 64 + fr;

#define STG_A(Q, KT) __builtin_amdgcn_global_load_lds( \
    (const __attribute__((address_space(1))) void*)(const void*)(aSrc + (size_t)((Q) * 32) * IN_DIM + (KT) * BKB), \
    (__attribute__((address_space(3))) void*)(ldsb + (Q) * 4096 + tid * 16), 16, 0, 0)
#define STG_B(Q, KT) __builtin_amdgcn_global_load_lds( \
    (const __attribute__((address_space(1))) void*)(const void*)(bSrc + (size_t)((Q) * 32) * IN_DIM + (KT) * BKB), \
    (__attribute__((address_space(3))) void*)(ldsb + BOFF + (Q) * 4096 + tid * 16), 16, 0, 0)
#define STG_TILE(KT) do { \
    STG_A(0, KT); STG_A(1, KT); STG_A(2, KT); STG_A(3, KT); \
    STG_B(0, KT); STG_B(1, KT); STG_B(2, KT); STG_B(3, KT); \
    SB0; } while (0)

#define SCV4(D0, D1, D2, D3, G) do { \
    asm volatile("global_load_dword %0, %1, off"            : "=v"(D0) : "v"(scp + (size_t)(G) * OUT_DIM)); \
    asm volatile("global_load_dword %0, %1, off offset:64"  : "=v"(D1) : "v"(scp + (size_t)(G) * OUT_DIM)); \
    asm volatile("global_load_dword %0, %1, off offset:128" : "=v"(D2) : "v"(scp + (size_t)(G) * OUT_DIM)); \
    asm volatile("global_load_dword %0, %1, off offset:192" : "=v"(D3) : "v"(scp + (size_t)(G) * OUT_DIM)); \
    SB0; } while (0)

// column j: 4 slabs x (2 chained MFMAs) + dequant into f32 master acc
#define QUADJ(J, CJ) do { \
    _Pragma("unroll") \
    for (int i = 0; i < 4; ++i) { \
        i32x4 tq = __builtin_amdgcn_mfma_i32_16x16x64_i8(a[i][0], b[J][0], (i32x4){0,0,0,0}, 0, 0, 0); \
        tq       = __builtin_amdgcn_mfma_i32_16x16x64_i8(a[i][1], b[J][1], tq, 0, 0, 0); \
        _Pragma("unroll") \
        for (int e = 0; e < 4; ++e) accf[i][J][e] += (float)tq[e] * (CJ); \
    } } while (0)

    f32x4 accf[4][4];
    #pragma unroll
    for (int i = 0; i < 4; ++i)
        #pragma unroll
        for (int j = 0; j < 4; ++j) accf[i][j] = (f32x4){0.f, 0.f, 0.f, 0.f};

    float c0, c1, c2, c3, n0 = 0.f, n1 = 0.f, n2 = 0.f, n3 = 0.f;

    // prologue: stage tile 0 + group-0 scales, full drain
    STG_TILE(0);
    SCV4(c0, c1, c2, c3, 0);
    WAITV(0);
    __builtin_amdgcn_s_barrier();
    SB0;

    for (int t = 0; t < NKT; ++t) {
        const bool haveN = (t + 1 < NKT);

        i32x4 a[4][2], b[4][2];
        // 16 ds_reads of tile t (square waves: A x2, B x2 re-read)
        #pragma unroll
        for (int i = 0; i < 4; ++i) {
            LDSR(a[i][0], aB0 + i * 2048);
            LDSR(a[i][1], aB1 + i * 2048);
        }
        #pragma unroll
        for (int j = 0; j < 4; ++j) {
            LDSR(b[j][0], bB0 + j * 2048);
            LDSR(b[j][1], bB1 + j * 2048);
        }
        WAITL(0);                       // this wave's frags in regs
        __builtin_amdgcn_s_barrier();   // all waves done reading -> buffer free
        SB0;                            // nothing may hoist above the barrier

        // restage IMMEDIATELY post-drain (r7 L2 law), + next-group scales
        if (haveN) {
            SCV4(n0, n1, n2, n3, t + 1);
            STG_TILE(t + 1);
        }
        SB0;

        __builtin_amdgcn_s_setprio(1);
        QUADJ(0, c0); QUADJ(1, c1); QUADJ(2, c2); QUADJ(3, c3);
        __builtin_amdgcn_s_setprio(0);

        WAITV(0);                       // tile t+1 DMA + scales landed
        __builtin_amdgcn_s_barrier();
        SB0;
        if (haveN) { c0 = n0; c1 = n1; c2 = n2; c3 = n3; }
    }

    // ---- epilogue: * sx[row], + bias[col] ----
    #pragma unroll
    for (int i = 0; i < 4; ++i) {
        const int row = bm * BM + wr * 64 + i * 16 + fko * 4;
        const f32x4 sxv = *(const f32x4*)(sx + row);
        #pragma unroll
        for (int j = 0; j < 4; ++j) {
            const int col = bn * BN + wc * 64 + j * 16 + fr;
            const float bv = bias[col];
            #pragma unroll
            for (int e = 0; e < 4; ++e)
                out[(size_t)(row + e) * OUT_DIM + col] = accf[i][j][e] * sxv[e] + bv;
        }
    }

#undef STG_A
#undef STG_B
#undef STG_TILE
#undef SCV4
#undef QUADJ
}

// ---- fallback (no workspace): round-1 proven kernel ----
__global__ __launch_bounds__(256) void awq_gemm_fb(
    const float* __restrict__ x, const int* __restrict__ wq,
    const float* __restrict__ scales, const float* __restrict__ s,
    const float* __restrict__ bias, float* __restrict__ out)
{
    __shared__ short As[128][32];
    __shared__ short Bs[128][32];
    const int tid = threadIdx.x, lane = tid & 63, wave = tid >> 6;
    const int nbn = OUT_DIM / 128;
    const int bm = blockIdx.x / nbn, bn = blockIdx.x % nbn;
    const int srow = tid >> 1, scol = (tid & 1) * 16;
    const int wm = (wave >> 1) * 64, wn = (wave & 1) * 64;
    f32x4 acc[4][4];
    #pragma unroll
    for (int i = 0; i < 4; ++i)
        #pragma unroll
        for (int j = 0; j < 4; ++j) acc[i][j] = (f32x4){0.f, 0.f, 0.f, 0.f};
    const float* xrow = x + (size_t)(bm * 128 + srow) * IN_DIM;
    const int* wrow = wq + (size_t)(bn * 128 + srow) * IN_DIM;
    const float* scrow = scales + (size_t)(bn * 128 + srow) * NGROUPS;
    const int fr = lane & 15, fk = (lane >> 4) * 8, fq = lane >> 4;
    for (int kt = 0; kt < IN_DIM / 32; ++kt) {
        const int k0 = kt * 32;
        {
            const float* xp = xrow + k0 + scol;
            const float* sp = s + k0 + scol;
            short tmp[16];
            #pragma unroll
            for (int q = 0; q < 4; ++q) {
                f32x4 xv = *(const f32x4*)(xp + q * 4);
                f32x4 sv = *(const f32x4*)(sp + q * 4);
                #pragma unroll
                for (int e = 0; e < 4; ++e) tmp[q * 4 + e] = f2bf(xv[e] / sv[e]);
            }
            #pragma unroll
            for (int e = 0; e < 16; ++e) As[srow][scol + e] = tmp[e];
        }
        {
            const float sc = scrow[kt >> 2];
            const int* wp = wrow + k0 + scol;
            short tmp[16];
            #pragma unroll
            for (int q = 0; q < 4; ++q) {
                i32x4 wv = *(const i32x4*)(wp + q * 4);
                #pragma unroll
                for (int e = 0; e < 4; ++e) tmp[q * 4 + e] = f2bf((float)wv[e] * sc);
            }
            #pragma unroll
            for (int e = 0; e < 16; ++e) Bs[srow][scol + e] = tmp[e];
        }
        __syncthreads();
        bf16x8 a[4], b[4];
        #pragma unroll
        for (int i = 0; i < 4; ++i) a[i] = *(const bf16x8*)&As[wm + i * 16 + fr][fk];
        #pragma unroll
        for (int j = 0; j < 4; ++j) b[j] = *(const bf16x8*)&Bs[wn + j * 16 + fr][fk];
        #pragma unroll
        for (int i = 0; i < 4; ++i)
            #pragma unroll
            for (int j = 0; j < 4; ++j)
                acc[i][j] = __builtin_amdgcn_mfma_f32_16x16x32_bf16(a[i], b[j], acc[i][j], 0, 0, 0);
        __syncthreads();
    }
    #pragma unroll
    for (int i = 0; i < 4; ++i) {
        const int row = bm * 128 + wm + i * 16 + fq * 4;
        #pragma unroll
        for (int j = 0; j < 4; ++j) {
            const int col = bn * 128 + wn + j * 16 + fr;
            const float bv = bias[col];
            #pragma unroll
            for (int e = 0; e < 4; ++e)
                out[(size_t)(row + e) * OUT_DIM + col] = acc[i][j][e] + bv;
        }
    }
}

extern "C" void kernel_launch(void* const* d_in, const int* in_sizes, int n_in,
                              void* d_out, int out_size, void* d_ws, size_t ws_size,
                              hipStream_t stream) {
    const float* x      = (const float*)d_in[0];
    const int*   wq     = (const int*)  d_in[1];
    const float* scales = (const float*)d_in[2];
    const float* s      = (const float*)d_in[3];
    const float* bias   = (const float*)d_in[4];
    float* out = (float*)d_out;

    // ws layout (16B-aligned): Aq 8MB | sx 8KB | Bq 43MB | scT 1.4MB
    const size_t off_sx = (size_t)TOKENS * IN_DIM;             // 8388608
    const size_t off_bq = off_sx + 8192;
    const size_t off_sc = off_bq + (size_t)OUT_DIM * IN_DIM;
    const size_t need   = off_sc + (size_t)OUT_DIM * NGROUPS * 4;  // ~54.9MB

    if (ws_size >= need) {
        char*  Aq  = (char*)d_ws;
        float* sxw = (float*)((char*)d_ws + off_sx);
        char*  Bq  = (char*)d_ws + off_bq;
        float* scT = (float*)((char*)d_ws + off_sc);
        prep_fused<<<PREP_GRID, 256, 0, stream>>>(x, wq, scales, s, Aq, sxw, Bq, scT);
        awq_gemm_i8<<<1408, THREADS, 0, stream>>>(Aq, Bq, scT, sxw, bias, out);
    } else {
        awq_gemm_fb<<<(TOKENS / 128) * (OUT_DIM / 128), 256, 0, stream>>>(x, wq, scales, s, bias, out);
    }
}